// Round 17
// baseline (24.960 us; speedup 1.0000x reference)
//
#include <hip/hip_runtime.h>
#include <hip/hip_fp16.h>
#include <math.h>

namespace {

constexpr int B_ = 4;
constexpr int N_ = 512;
constexpr int D_ = 256;
constexpr int L_ = 128;
constexpr int L2_ = L_ / 2;  // 64 packed l-pairs
constexpr int TI = 4;        // i-rows per dist block

typedef _Float16 v2h __attribute__((ext_vector_type(2)));
typedef float v4f __attribute__((ext_vector_type(4)));

// xs_h2[b][l2][n] = f16x2( a[2l2]*dot(x[b][n],W[2l2]), a[2l2+1]*dot(...) )
// 512 blocks (8 l x 64 n tiles), XCD-pinned, 2 blocks/CU.
// SINGLE-BARRIER staging (R16, unchanged).
__global__ __launch_bounds__(256) void proj_kernel(
    const float* __restrict__ x, const float* __restrict__ W,
    const float* __restrict__ a, unsigned* __restrict__ xs_u) {
  const int bid = blockIdx.x;       // 0..511
  const int xcd = bid & 7;          // round-robin XCD assignment
  const int b = xcd >> 1;           // batch pinned to XCD pair
  const int tile = ((xcd & 1) << 6) + (bid >> 3);  // 0..127
  const int l0 = (tile >> 3) * 8;   // 16 l-tiles of 8
  const int n0 = (tile & 7) * 64;   // 8 n-tiles of 64

  const int t = threadIdx.x;

  __shared__ float wl_s[8 * 256];    // 8 KB W tile
  __shared__ float xl[2][64 * 129];  // 66 KB, both halves, odd stride 129

  const int n = t & 63;
  const int lg = t >> 6;  // 0..3, wave-uniform; 2 l each

  // stage W tile (8 l x 256 d), coalesced float4
  {
    const float4* __restrict__ Wsrc =
        reinterpret_cast<const float4*>(W + (size_t)l0 * D_);
    float4* wdst = reinterpret_cast<float4*>(wl_s);
#pragma unroll
    for (int k = 0; k < 2; ++k) wdst[t + k * 256] = Wsrc[t + k * 256];
  }
  // stage x[b][n0..+64][0..256] -> LDS, all 16 float4 loads in flight
  {
    const v4f* __restrict__ xsrc =
        reinterpret_cast<const v4f*>(x + ((size_t)(b * N_ + n0)) * D_);
#pragma unroll
    for (int k = 0; k < 16; ++k) {
      const int f = t + k * 256;  // 0..4095 global float4 index
      const int sn = f >> 6;      // local n
      const int sq = f & 63;      // float4 within 256-d row
      const v4f v = __builtin_nontemporal_load(&xsrc[f]);
      float* dst = &xl[sq >> 5][sn * 129 + (sq & 31) * 4];
      dst[0] = v.x; dst[1] = v.y; dst[2] = v.z; dst[3] = v.w;
    }
  }
  __syncthreads();  // the ONLY barrier

  float acc0 = 0.f, acc1 = 0.f;
  const float4* __restrict__ w4 = reinterpret_cast<const float4*>(wl_s);
#pragma unroll 4
  for (int d4g = 0; d4g < 64; ++d4g) {
    const float* __restrict__ xr = &xl[d4g >> 5][n * 129 + (d4g & 31) * 4];
    const float x0 = xr[0];
    const float x1 = xr[1];
    const float x2 = xr[2];
    const float x3 = xr[3];
    const float4 w0 = w4[(lg * 2 + 0) * 64 + d4g];  // broadcast
    const float4 w1 = w4[(lg * 2 + 1) * 64 + d4g];  // broadcast
    acc0 += x0 * w0.x + x1 * w0.y + x2 * w0.z + x3 * w0.w;
    acc1 += x0 * w1.x + x1 * w1.y + x2 * w1.z + x3 * w1.w;
  }

  const int lbase = l0 + lg * 2;  // even -> one f16x2 pair per thread
  const float s0 = acc0 * a[lbase + 0];
  const float s1 = acc1 * a[lbase + 1];
  const auto p01 = __builtin_amdgcn_cvt_pkrtz(s0, s1);  // __fp16x2
  xs_u[((size_t)b * L2_ + (lbase >> 1)) * N_ + n0 + n] =
      __builtin_bit_cast(unsigned, p01);  // coalesced
}

// Fused dist+softmax, XCD-pinned, TI=4, f16x2, constant-shift softmax.
// ZERO LDS in the main loop: lane u holds xi[u][0..3] in VGPRs; per-u
// broadcast via v_readlane (SGPR) feeds v_pk_sub_f16 directly.
__global__ __launch_bounds__(512, 4) void dist_softmax_kernel(
    const unsigned* __restrict__ xs_u, const float* __restrict__ adj,
    const int* __restrict__ box_num, const float* __restrict__ a,
    float* __restrict__ out) {
  const int bid = blockIdx.x;       // 0..511
  const int xcd = bid & 7;
  const int b = xcd >> 1;
  const int tile = ((xcd & 1) << 6) + (bid >> 3);  // 0..127
  const int i0 = tile * TI;

  const int t = threadIdx.x;
  const int j = t;
  const int lane = t & 63;
  const int wid = t >> 6;
  const int bn = box_num[b];
  const unsigned* __restrict__ xs_b = xs_u + (size_t)b * L2_ * N_;

  __shared__ float red[8][TI];
  __shared__ float rsinv_s[TI];

  // sum(a): per-wave butterfly, no LDS, no barrier
  float sum_a;
  {
    float sa = a[lane] + a[lane + 64];
#pragma unroll
    for (int off = 1; off < 64; off <<= 1) sa += __shfl_xor(sa, off);
    sum_a = sa;
  }

  // lane u holds xi[u][r] = xs_b[u*N + i0 + r] (4 gather loads, once)
  unsigned xiA[TI];
#pragma unroll
  for (int r = 0; r < TI; ++r) {
    xiA[r] = xs_b[lane * N_ + i0 + r];
  }

  // issue ALL 64 xj loads — maximal within-wave latency hiding
  unsigned xj[64];
#pragma unroll
  for (int u = 0; u < 64; ++u) {
    xj[u] = xs_b[u * N_ + j];  // coalesced b32, L2-resident
  }

  float acc[TI];
#pragma unroll
  for (int r = 0; r < TI; ++r) acc[r] = 0.f;

  const v2h one2 = {(_Float16)1.0f, (_Float16)1.0f};

#pragma unroll
  for (int u = 0; u < 64; ++u) {
    const unsigned xjw = xj[u];
#pragma unroll
    for (int r = 0; r < TI; ++r) {
      const unsigned s = __builtin_amdgcn_readlane(xiA[r], u);  // SGPR bcast
      const v2h d = __builtin_bit_cast(v2h, s) -
                    __builtin_bit_cast(v2h, xjw);  // v_pk_sub_f16 (s,v)
      const unsigned du = __builtin_bit_cast(unsigned, d) & 0x7FFF7FFFu;
      acc[r] = __builtin_amdgcn_fdot2(__builtin_bit_cast(v2h, du), one2,
                                      acc[r], false);
    }
  }

  const bool vj = j < bn;
  float e[TI];
  const float* __restrict__ adjp = adj + ((size_t)(b * N_ + i0)) * N_ + j;
#pragma unroll
  for (int r = 0; r < TI; ++r) {
    const bool vi = (i0 + r) < bn;
    const float d = acc[r] - ((vi && vj) ? 0.f : sum_a);  // + mask*sum(a)
    const float val = d >= 0.f ? d : 0.01f * d;           // leaky_relu
    const float av = __builtin_nontemporal_load(&adjp[(size_t)r * N_]);
    e[r] = av * __expf(val - 64.0f);  // constant shift, softmax-invariant
  }

  // ---- row sum over 512 j ----
  {
    float wsum[TI];
#pragma unroll
    for (int r = 0; r < TI; ++r) {
      float s = e[r];
#pragma unroll
      for (int off = 1; off < 64; off <<= 1) s += __shfl_xor(s, off);
      wsum[r] = s;
    }
    if (lane == 0) {
#pragma unroll
      for (int r = 0; r < TI; ++r) red[wid][r] = wsum[r];
    }
  }
  __syncthreads();
  if (t < TI) {
    float s = red[0][t];
#pragma unroll
    for (int w = 1; w < 8; ++w) s += red[w][t];
    rsinv_s[t] = 1.0f / s;
  }
  __syncthreads();

  float* __restrict__ op = out + ((size_t)(b * N_ + i0)) * N_ + j;
#pragma unroll
  for (int r = 0; r < TI; ++r) {
    __builtin_nontemporal_store(e[r] * rsinv_s[r] + 1e-10f,
                                &op[(size_t)r * N_]);
  }
}

}  // namespace

extern "C" void kernel_launch(void* const* d_in, const int* in_sizes, int n_in,
                              void* d_out, int out_size, void* d_ws,
                              size_t ws_size, hipStream_t stream) {
  const float* x = (const float*)d_in[0];    // (B,N,D) f32
  const float* adj = (const float*)d_in[1];  // (B,N,N) f32
  const int* box_num = (const int*)d_in[2];  // (B,1) int32
  const float* W = (const float*)d_in[3];    // (L,D) f32
  const float* a = (const float*)d_in[4];    // (L,) f32
  float* out = (float*)d_out;                // (B,N,N) f32
  unsigned* xs_u = (unsigned*)d_ws;          // B*64*512 u32 = 512 KB scratch

  proj_kernel<<<512, 256, 0, stream>>>(x, W, a, xs_u);
  dist_softmax_kernel<<<512, 512, 0, stream>>>(xs_u, adj, box_num, a, out);
}

// Round 18
// 24.558 us; speedup vs baseline: 1.0164x; 1.0164x over previous
//
#include <hip/hip_runtime.h>
#include <hip/hip_fp16.h>
#include <math.h>

namespace {

constexpr int B_ = 4;
constexpr int N_ = 512;
constexpr int D_ = 256;
constexpr int L_ = 128;
constexpr int L2_ = L_ / 2;  // 64 packed l-pairs
constexpr int TI = 8;        // i-rows per dist block (l-split groups)

typedef _Float16 v2h __attribute__((ext_vector_type(2)));
typedef float v4f __attribute__((ext_vector_type(4)));

// xs_h2[b][l2][n] = f16x2( a[2l2]*dot(x[b][n],W[2l2]), a[2l2+1]*dot(...) )
// R16 proj (single-barrier staging), unchanged.
__global__ __launch_bounds__(256) void proj_kernel(
    const float* __restrict__ x, const float* __restrict__ W,
    const float* __restrict__ a, unsigned* __restrict__ xs_u) {
  const int bid = blockIdx.x;       // 0..511
  const int xcd = bid & 7;          // round-robin XCD assignment
  const int b = xcd >> 1;           // batch pinned to XCD pair
  const int tile = ((xcd & 1) << 6) + (bid >> 3);  // 0..127
  const int l0 = (tile >> 3) * 8;   // 16 l-tiles of 8
  const int n0 = (tile & 7) * 64;   // 8 n-tiles of 64

  const int t = threadIdx.x;

  __shared__ float wl_s[8 * 256];    // 8 KB W tile
  __shared__ float xl[2][64 * 129];  // 66 KB, both halves, odd stride 129

  const int n = t & 63;
  const int lg = t >> 6;  // 0..3, wave-uniform; 2 l each

  {
    const float4* __restrict__ Wsrc =
        reinterpret_cast<const float4*>(W + (size_t)l0 * D_);
    float4* wdst = reinterpret_cast<float4*>(wl_s);
#pragma unroll
    for (int k = 0; k < 2; ++k) wdst[t + k * 256] = Wsrc[t + k * 256];
  }
  {
    const v4f* __restrict__ xsrc =
        reinterpret_cast<const v4f*>(x + ((size_t)(b * N_ + n0)) * D_);
#pragma unroll
    for (int k = 0; k < 16; ++k) {
      const int f = t + k * 256;  // 0..4095 global float4 index
      const int sn = f >> 6;      // local n
      const int sq = f & 63;      // float4 within 256-d row
      const v4f v = __builtin_nontemporal_load(&xsrc[f]);
      float* dst = &xl[sq >> 5][sn * 129 + (sq & 31) * 4];
      dst[0] = v.x; dst[1] = v.y; dst[2] = v.z; dst[3] = v.w;
    }
  }
  __syncthreads();  // the ONLY barrier

  float acc0 = 0.f, acc1 = 0.f;
  const float4* __restrict__ w4 = reinterpret_cast<const float4*>(wl_s);
#pragma unroll 4
  for (int d4g = 0; d4g < 64; ++d4g) {
    const float* __restrict__ xr = &xl[d4g >> 5][n * 129 + (d4g & 31) * 4];
    const float x0 = xr[0];
    const float x1 = xr[1];
    const float x2 = xr[2];
    const float x3 = xr[3];
    const float4 w0 = w4[(lg * 2 + 0) * 64 + d4g];  // broadcast
    const float4 w1 = w4[(lg * 2 + 1) * 64 + d4g];  // broadcast
    acc0 += x0 * w0.x + x1 * w0.y + x2 * w0.z + x3 * w0.w;
    acc1 += x0 * w1.x + x1 * w1.y + x2 * w1.z + x3 * w1.w;
  }

  const int lbase = l0 + lg * 2;
  const float s0 = acc0 * a[lbase + 0];
  const float s1 = acc1 * a[lbase + 1];
  const auto p01 = __builtin_amdgcn_cvt_pkrtz(s0, s1);  // __fp16x2
  xs_u[((size_t)b * L2_ + (lbase >> 1)) * N_ + n0 + n] =
      __builtin_bit_cast(unsigned, p01);  // coalesced
}

// dist+softmax: TI=8 via l-split. 256 blocks x 1024 threads (4 waves/SIMD).
// Group g = t>>9 covers l2 in [32g, 32g+32) for the same 8 rows; partials
// exchanged in LDS; group g finalizes rows i0+4g..i0+4g+3. f16x2 math,
// constant-shift softmax, XCD-pinned. Halves xj L2 traffic vs TI=4.
__global__ __launch_bounds__(1024) void dist_softmax_kernel(
    const unsigned* __restrict__ xs_u, const float* __restrict__ adj,
    const int* __restrict__ box_num, const float* __restrict__ a,
    float* __restrict__ out) {
  const int bid = blockIdx.x;       // 0..255
  const int xcd = bid & 7;
  const int b = xcd >> 1;
  const int tile = ((xcd & 1) << 5) + (bid >> 3);  // 0..63
  const int i0 = tile * TI;

  const int t = threadIdx.x;
  const int g = t >> 9;    // l-half group
  const int j = t & 511;   // column
  const int lane = t & 63;
  const int wid = t >> 6;  // 0..15
  const int bn = box_num[b];
  const unsigned* __restrict__ xs_b = xs_u + (size_t)b * L2_ * N_;

  __shared__ unsigned xi_s[L2_ * TI];   // [l2][r] f16x2, 2 KB
  __shared__ float cross[2][512][4];    // 16 KB partial exchange
  __shared__ float red[16][4];
  __shared__ float rsinv_s[2][4];

  // stage xi: 512 u32, threads t<512: (l2 = t>>3, r = t&7)
  if (t < L2_ * TI) {
    xi_s[t] = xs_b[(t >> 3) * N_ + i0 + (t & 7)];
  }

  // sum(a): per-wave butterfly, no LDS
  float sum_a;
  {
    float sa = a[lane] + a[lane + 64];
#pragma unroll
    for (int off = 1; off < 64; off <<= 1) sa += __shfl_xor(sa, off);
    sum_a = sa;
  }
  __syncthreads();

  float acc[TI];
#pragma unroll
  for (int r = 0; r < TI; ++r) acc[r] = 0.f;

  const v2h one2 = {(_Float16)1.0f, (_Float16)1.0f};
  const uint4* __restrict__ xi4 = reinterpret_cast<const uint4*>(xi_s);
  const int u0 = g * 32;

  // issue this group's 32 xj loads up front
  unsigned xj[32];
#pragma unroll
  for (int u = 0; u < 32; ++u) {
    xj[u] = xs_b[(u0 + u) * N_ + j];  // coalesced b32, L2-resident
  }

#pragma unroll
  for (int u = 0; u < 32; ++u) {
    const unsigned xjw = xj[u];
    const uint4 xiA = xi4[(u0 + u) * 2];      // broadcast b128 (r=0..3)
    const uint4 xiB = xi4[(u0 + u) * 2 + 1];  // r=4..7
    const unsigned xiw[8] = {xiA.x, xiA.y, xiA.z, xiA.w,
                             xiB.x, xiB.y, xiB.z, xiB.w};
#pragma unroll
    for (int r = 0; r < TI; ++r) {
      const v2h d = __builtin_bit_cast(v2h, xiw[r]) -
                    __builtin_bit_cast(v2h, xjw);  // v_pk_sub_f16
      const unsigned du = __builtin_bit_cast(unsigned, d) & 0x7FFF7FFFu;
      acc[r] = __builtin_amdgcn_fdot2(__builtin_bit_cast(v2h, du), one2,
                                      acc[r], false);
    }
  }

  // exchange: give the other group the 4 rows it finalizes
  {
    float4 c;
    c.x = acc[(1 - g) * 4 + 0];
    c.y = acc[(1 - g) * 4 + 1];
    c.z = acc[(1 - g) * 4 + 2];
    c.w = acc[(1 - g) * 4 + 3];
    *reinterpret_cast<float4*>(&cross[g][j][0]) = c;
  }
  __syncthreads();

  const bool vj = j < bn;
  float e[4];
  const float* __restrict__ adjp =
      adj + ((size_t)(b * N_ + i0 + g * 4)) * N_ + j;
  {
    const float4 c = *reinterpret_cast<const float4*>(&cross[1 - g][j][0]);
    const float oth[4] = {c.x, c.y, c.z, c.w};
#pragma unroll
    for (int q = 0; q < 4; ++q) {
      const int row = i0 + g * 4 + q;
      const float dtot = acc[g * 4 + q] + oth[q] -
                         (((row < bn) && vj) ? 0.f : sum_a);  // + mask*sum_a
      const float val = dtot >= 0.f ? dtot : 0.01f * dtot;    // leaky_relu
      const float av = __builtin_nontemporal_load(&adjp[(size_t)q * N_]);
      e[q] = av * __expf(val - 64.0f);  // constant shift, softmax-invariant
    }
  }

  // ---- row sum over this group's 512 j ----
  {
    float ws[4];
#pragma unroll
    for (int q = 0; q < 4; ++q) {
      float s = e[q];
#pragma unroll
      for (int off = 1; off < 64; off <<= 1) s += __shfl_xor(s, off);
      ws[q] = s;
    }
    if (lane == 0) {
#pragma unroll
      for (int q = 0; q < 4; ++q) red[wid][q] = ws[q];
    }
  }
  __syncthreads();
  if (t < 8) {
    const int g2 = t >> 2, q = t & 3;
    float s = red[g2 * 8][q];
#pragma unroll
    for (int w = 1; w < 8; ++w) s += red[g2 * 8 + w][q];
    rsinv_s[g2][q] = 1.0f / s;
  }
  __syncthreads();

  float* __restrict__ op = out + ((size_t)(b * N_ + i0 + g * 4)) * N_ + j;
#pragma unroll
  for (int q = 0; q < 4; ++q) {
    __builtin_nontemporal_store(e[q] * rsinv_s[g][q] + 1e-10f,
                                &op[(size_t)q * N_]);
  }
}

}  // namespace

extern "C" void kernel_launch(void* const* d_in, const int* in_sizes, int n_in,
                              void* d_out, int out_size, void* d_ws,
                              size_t ws_size, hipStream_t stream) {
  const float* x = (const float*)d_in[0];    // (B,N,D) f32
  const float* adj = (const float*)d_in[1];  // (B,N,N) f32
  const int* box_num = (const int*)d_in[2];  // (B,1) int32
  const float* W = (const float*)d_in[3];    // (L,D) f32
  const float* a = (const float*)d_in[4];    // (L,) f32
  float* out = (float*)d_out;                // (B,N,N) f32
  unsigned* xs_u = (unsigned*)d_ws;          // B*64*512 u32 = 512 KB scratch

  proj_kernel<<<512, 256, 0, stream>>>(x, W, a, xs_u);
  dist_softmax_kernel<<<256, 1024, 0, stream>>>(xs_u, adj, box_num, a, out);
}

// Round 19
// 24.174 us; speedup vs baseline: 1.0325x; 1.0159x over previous
//
#include <hip/hip_runtime.h>
#include <hip/hip_fp16.h>
#include <math.h>

namespace {

constexpr int B_ = 4;
constexpr int N_ = 512;
constexpr int D_ = 256;
constexpr int L_ = 128;
constexpr int L2_ = L_ / 2;  // 64 packed l-pairs
constexpr int TI = 4;        // i-rows per dist block

typedef _Float16 v2h __attribute__((ext_vector_type(2)));
typedef float v4f __attribute__((ext_vector_type(4)));

// xs_h2[b][l2][n] = f16x2( a[2l2]*dot(x[b][n],W[2l2]), a[2l2+1]*dot(...) )
// 512 blocks (8 l x 64 n tiles), XCD-pinned, 2 blocks/CU.
// SINGLE-BARRIER staging: W + both x-halves (16 float4 loads all in flight),
// one __syncthreads, then full 256-d compute. f32 math.
__global__ __launch_bounds__(256) void proj_kernel(
    const float* __restrict__ x, const float* __restrict__ W,
    const float* __restrict__ a, unsigned* __restrict__ xs_u) {
  const int bid = blockIdx.x;       // 0..511
  const int xcd = bid & 7;          // round-robin XCD assignment
  const int b = xcd >> 1;           // batch pinned to XCD pair
  const int tile = ((xcd & 1) << 6) + (bid >> 3);  // 0..127
  const int l0 = (tile >> 3) * 8;   // 16 l-tiles of 8
  const int n0 = (tile & 7) * 64;   // 8 n-tiles of 64

  const int t = threadIdx.x;

  __shared__ float wl_s[8 * 256];    // 8 KB W tile (flat [l][d4] float4 view)
  __shared__ float xl[2][64 * 129];  // 66 KB, both halves, odd stride 129

  const int n = t & 63;
  const int lg = t >> 6;  // 0..3, wave-uniform; 2 l each

  // stage W tile (8 l x 256 d), coalesced float4
  {
    const float4* __restrict__ Wsrc =
        reinterpret_cast<const float4*>(W + (size_t)l0 * D_);
    float4* wdst = reinterpret_cast<float4*>(wl_s);
#pragma unroll
    for (int k = 0; k < 2; ++k) wdst[t + k * 256] = Wsrc[t + k * 256];
  }
  // stage x[b][n0..+64][0..256] -> LDS, all 16 float4 loads in flight
  {
    const v4f* __restrict__ xsrc =
        reinterpret_cast<const v4f*>(x + ((size_t)(b * N_ + n0)) * D_);
#pragma unroll
    for (int k = 0; k < 16; ++k) {
      const int f = t + k * 256;  // 0..4095 global float4 index
      const int sn = f >> 6;      // local n
      const int sq = f & 63;      // float4 within 256-d row
      const v4f v = __builtin_nontemporal_load(&xsrc[f]);
      float* dst = &xl[sq >> 5][sn * 129 + (sq & 31) * 4];
      dst[0] = v.x; dst[1] = v.y; dst[2] = v.z; dst[3] = v.w;
    }
  }
  __syncthreads();  // the ONLY barrier

  float acc0 = 0.f, acc1 = 0.f;
  const float4* __restrict__ w4 = reinterpret_cast<const float4*>(wl_s);
#pragma unroll 4
  for (int d4g = 0; d4g < 64; ++d4g) {
    const float* __restrict__ xr = &xl[d4g >> 5][n * 129 + (d4g & 31) * 4];
    const float x0 = xr[0];
    const float x1 = xr[1];
    const float x2 = xr[2];
    const float x3 = xr[3];
    const float4 w0 = w4[(lg * 2 + 0) * 64 + d4g];  // broadcast
    const float4 w1 = w4[(lg * 2 + 1) * 64 + d4g];  // broadcast
    acc0 += x0 * w0.x + x1 * w0.y + x2 * w0.z + x3 * w0.w;
    acc1 += x0 * w1.x + x1 * w1.y + x2 * w1.z + x3 * w1.w;
  }

  const int lbase = l0 + lg * 2;  // even -> one f16x2 pair per thread
  const float s0 = acc0 * a[lbase + 0];
  const float s1 = acc1 * a[lbase + 1];
  const auto p01 = __builtin_amdgcn_cvt_pkrtz(s0, s1);  // __fp16x2
  xs_u[((size_t)b * L2_ + (lbase >> 1)) * N_ + n0 + n] =
      __builtin_bit_cast(unsigned, p01);  // coalesced
}

// Fused dist+softmax, XCD-pinned, TI=4, f16x2 math, 64-deep xj prefetch.
// CONSTANT-SHIFT softmax (C=64): row-max reduction removed entirely
// (softmax is shift-invariant; leaky-relu bounds val in [-0.75, ~110]).
__global__ __launch_bounds__(512, 4) void dist_softmax_kernel(
    const unsigned* __restrict__ xs_u, const float* __restrict__ adj,
    const int* __restrict__ box_num, const float* __restrict__ a,
    float* __restrict__ out) {
  const int bid = blockIdx.x;       // 0..511
  const int xcd = bid & 7;
  const int b = xcd >> 1;
  const int tile = ((xcd & 1) << 6) + (bid >> 3);  // 0..127
  const int i0 = tile * TI;

  const int t = threadIdx.x;
  const int j = t;
  const int bn = box_num[b];
  const unsigned* __restrict__ xs_b = xs_u + (size_t)b * L2_ * N_;

  __shared__ unsigned xi_s[L2_ * TI];  // [l2][r] f16x2, 1 KB, b128 broadcast
  __shared__ float red[8][TI];
  __shared__ float sa_l[2];
  __shared__ float rsinv_s[TI];

  // stage xi pairs: 256 u32, threads t<256: (l2 = t>>2, r = t&3)
  if (t < L2_ * TI) {
    xi_s[t] = xs_b[(t >> 2) * N_ + i0 + (t & 3)];
  }

  // sum(a) prologue (f32, exact)
  {
    float sa = (t < L_) ? a[t] : 0.f;
#pragma unroll
    for (int off = 1; off < 64; off <<= 1) sa += __shfl_xor(sa, off);
    if (t == 0) sa_l[0] = sa;
    if (t == 64) sa_l[1] = sa;
  }
  __syncthreads();
  const float sum_a = sa_l[0] + sa_l[1];

  float acc[TI];
#pragma unroll
  for (int r = 0; r < TI; ++r) acc[r] = 0.f;

  const v2h one2 = {(_Float16)1.0f, (_Float16)1.0f};
  const uint4* __restrict__ xi4 = reinterpret_cast<const uint4*>(xi_s);

  // issue ALL 64 xj loads first — maximal within-wave latency hiding
  unsigned xj[64];
#pragma unroll
  for (int u = 0; u < 64; ++u) {
    xj[u] = xs_b[u * N_ + j];  // coalesced b32, L2-resident
  }

#pragma unroll
  for (int u = 0; u < 64; ++u) {
    const uint4 xi = xi4[u];  // broadcast ds_read_b128
    const unsigned xjw = xj[u];
    const unsigned xiw[4] = {xi.x, xi.y, xi.z, xi.w};
#pragma unroll
    for (int r = 0; r < TI; ++r) {
      const v2h d = __builtin_bit_cast(v2h, xiw[r]) -
                    __builtin_bit_cast(v2h, xjw);  // v_pk_sub_f16
      const unsigned du = __builtin_bit_cast(unsigned, d) & 0x7FFF7FFFu;
      acc[r] = __builtin_amdgcn_fdot2(__builtin_bit_cast(v2h, du), one2,
                                      acc[r], false);
    }
  }

  const bool vj = j < bn;
  float e[TI];
  const float* __restrict__ adjp = adj + ((size_t)(b * N_ + i0)) * N_ + j;
#pragma unroll
  for (int r = 0; r < TI; ++r) {
    const bool vi = (i0 + r) < bn;
    const float d = acc[r] - ((vi && vj) ? 0.f : sum_a);  // + mask*sum(a)
    const float val = d >= 0.f ? d : 0.01f * d;           // leaky_relu
    const float av = __builtin_nontemporal_load(&adjp[(size_t)r * N_]);
    e[r] = av * __expf(val - 64.0f);  // constant shift, softmax-invariant
  }

  const int lane = t & 63;
  const int wid = t >> 6;

  // ---- row sum over 512 j ----
  {
    float wsum[TI];
#pragma unroll
    for (int r = 0; r < TI; ++r) {
      float s = e[r];
#pragma unroll
      for (int off = 1; off < 64; off <<= 1) s += __shfl_xor(s, off);
      wsum[r] = s;
    }
    if (lane == 0) {
#pragma unroll
      for (int r = 0; r < TI; ++r) red[wid][r] = wsum[r];
    }
  }
  __syncthreads();
  if (t < TI) {
    float s = red[0][t];
#pragma unroll
    for (int w = 1; w < 8; ++w) s += red[w][t];
    rsinv_s[t] = 1.0f / s;
  }
  __syncthreads();

  float* __restrict__ op = out + ((size_t)(b * N_ + i0)) * N_ + j;
#pragma unroll
  for (int r = 0; r < TI; ++r) {
    __builtin_nontemporal_store(e[r] * rsinv_s[r] + 1e-10f,
                                &op[(size_t)r * N_]);
  }
}

}  // namespace

extern "C" void kernel_launch(void* const* d_in, const int* in_sizes, int n_in,
                              void* d_out, int out_size, void* d_ws,
                              size_t ws_size, hipStream_t stream) {
  const float* x = (const float*)d_in[0];    // (B,N,D) f32
  const float* adj = (const float*)d_in[1];  // (B,N,N) f32
  const int* box_num = (const int*)d_in[2];  // (B,1) int32
  const float* W = (const float*)d_in[3];    // (L,D) f32
  const float* a = (const float*)d_in[4];    // (L,) f32
  float* out = (float*)d_out;                // (B,N,N) f32
  unsigned* xs_u = (unsigned*)d_ws;          // B*64*512 u32 = 512 KB scratch

  proj_kernel<<<512, 256, 0, stream>>>(x, W, a, xs_u);
  dist_softmax_kernel<<<512, 512, 0, stream>>>(xs_u, adj, box_num, a, out);
}